// Round 5
// baseline (218.010 us; speedup 1.0000x reference)
//
#include <hip/hip_runtime.h>
#include <hip/hip_bf16.h>
#include <stdint.h>

// Problem constants (fixed by setup_inputs)
#define TM 16384   // B rows of input
#define TN 4096    // O centers
#define TK 1024    // I feature dim

#define NT (TK / 64)   // 16 K-tiles per output tile
#define JT 4           // output tiles per block (persistent along N)

typedef __attribute__((ext_vector_type(8))) short bf16x8;
typedef __attribute__((ext_vector_type(4))) float f32x4;

static __device__ __forceinline__ ushort f2bf(float x) {
    __hip_bfloat16 h = __float2bfloat16(x);
    return *reinterpret_cast<ushort*>(&h);
}

// Convert one fp32 row (TK elems) to bf16 and emit its sum of squares.
__global__ __launch_bounds__(256) void rowsq_cvt(const float* __restrict__ src,
                                                 ushort* __restrict__ dst,
                                                 float* __restrict__ sq) {
    const int row = blockIdx.x;
    const int t = threadIdx.x;
    const size_t base = (size_t)row * TK + (size_t)t * 4;
    const f32x4 v = __builtin_nontemporal_load((const f32x4*)(src + base));
    float s = v.x * v.x + v.y * v.y + v.z * v.z + v.w * v.w;

    ushort4 b;
    b.x = f2bf(v.x); b.y = f2bf(v.y); b.z = f2bf(v.z); b.w = f2bf(v.w);
    *(ushort4*)(dst + base) = b;

#pragma unroll
    for (int off = 32; off > 0; off >>= 1) s += __shfl_down(s, off);

    __shared__ float red[4];
    const int lane = t & 63, wave = t >> 6;
    if (lane == 0) red[wave] = s;
    __syncthreads();
    if (t == 0) sq[row] = red[0] + red[1] + red[2] + red[3];
}

// f[o] = -1/(2*sigma^2), sigma = exp(log_sigma)
__global__ __launch_bounds__(256) void scale_k(const float* __restrict__ ls,
                                               float* __restrict__ f) {
    const int i = blockIdx.x * 256 + threadIdx.x;
    if (i < TN) f[i] = -0.5f * expf(-2.0f * ls[i]);
}

// ---- persistent 8-phase 256x256 bf16 MFMA GEMM with fused RBF epilogue ----
// LDS: [buf][A|B] panels of 256x64 bf16 = 128 KiB. 2-bit XOR swizzle:
// physical byte p holds logical byte p ^ ((((p>>9)&1)<<5) | (((p>>10)&1)<<6))
// (row bits 2,3 -> byte bits 5,6; involution; applied on the global SOURCE at
// stage time and on the ds_read address). NOTE: the k-step column offset must
// be folded with XOR (cX ^ 32-elems), NOT addition — bit-6 carry corrupts the
// row otherwise (round-4 bug).

#define STAGE(PAN, SRC, H) do {                                                \
    __builtin_amdgcn_global_load_lds(                                          \
        (const __attribute__((address_space(1))) void*)((SRC) + (size_t)(H) * 128 * TK), \
        (__attribute__((address_space(3))) void*)((PAN) + (H) * 8192 + wbase), \
        16, 0, 0);                                                             \
    __builtin_amdgcn_global_load_lds(                                          \
        (const __attribute__((address_space(1))) void*)((SRC) + (size_t)(H) * 128 * TK + 64 * TK), \
        (__attribute__((address_space(3))) void*)((PAN) + (H) * 8192 + 4096 + wbase), \
        16, 0, 0);                                                             \
} while (0)

// Staging-stream sources. A panel is identical for every output tile of this
// block (stream wraps &15). B panel advances along N every 16 K-tiles; wrap
// &63 keeps tail prefetch in-bounds (wrapped data is staged but never read).
#define ASRC(S) (gAl + (size_t)((S) & 15) * 64)
#define BSRC(S) (gBl + (size_t)(((S) & 63) >> 4) * (256 * (size_t)TK) + (size_t)((S) & 15) * 64)

#define READA(PAN, QM) do {                                                    \
    _Pragma("unroll") for (int _i = 0; _i < 4; ++_i)                           \
    _Pragma("unroll") for (int _k = 0; _k < 2; ++_k)                           \
        af[_i][_k] = *(const bf16x8*)((PAN) +                                  \
            (size_t)(rowA + (QM) * 64 + _i * 16) * 64 + (cX ^ (_k * 32)));     \
} while (0)

#define READB(PAN, QN) do {                                                    \
    _Pragma("unroll") for (int _n = 0; _n < 2; ++_n)                           \
    _Pragma("unroll") for (int _k = 0; _k < 2; ++_k)                           \
        bf[(QN) * 2 + _n][_k] = *(const bf16x8*)((PAN) +                       \
            (size_t)(rowB + (QN) * 32 + _n * 16) * 64 + (cX ^ (_k * 32)));     \
} while (0)

#define MFMA16(QM, QN)                                                         \
    _Pragma("unroll") for (int _i = 0; _i < 4; ++_i)                           \
    _Pragma("unroll") for (int _n = 0; _n < 2; ++_n)                           \
    _Pragma("unroll") for (int _k = 0; _k < 2; ++_k)                           \
        acc[(QM) * 4 + _i][(QN) * 2 + _n] =                                    \
            __builtin_amdgcn_mfma_f32_16x16x32_bf16(                           \
                af[_i][_k], bf[(QN) * 2 + _n][_k],                             \
                acc[(QM) * 4 + _i][(QN) * 2 + _n], 0, 0, 0)

#define PH_SYNC do {                                                           \
    __builtin_amdgcn_s_barrier();                                              \
    asm volatile("s_waitcnt lgkmcnt(0)" ::: "memory");                         \
    __builtin_amdgcn_sched_barrier(0);                                         \
    __builtin_amdgcn_s_setprio(1);                                             \
} while (0)

#define PH_END do {                                                            \
    __builtin_amdgcn_s_setprio(0);                                             \
    __builtin_amdgcn_s_barrier();                                              \
} while (0)

#define PH_END_VM do {                                                         \
    __builtin_amdgcn_s_setprio(0);                                             \
    asm volatile("s_waitcnt vmcnt(4)" ::: "memory");                           \
    __builtin_amdgcn_s_barrier();                                              \
} while (0)

__global__ __launch_bounds__(512) void rbf_gemm(const ushort* __restrict__ A,
                                                const ushort* __restrict__ B,
                                                const float* __restrict__ xsq,
                                                const float* __restrict__ csq,
                                                const float* __restrict__ fsc,
                                                float* __restrict__ out) {
    __shared__ __align__(16) ushort lds[65536];  // 128 KiB

    // 256 persistent blocks (1/CU), 8 XCDs x 32 contiguous wgs.
    // Same-bm blocks land on the same XCD (shared 512 KB A panel in L2).
    const int bid = blockIdx.x;
    const int wg = (bid & 7) * 32 + (bid >> 3);
    const int bm = wg >> 2;            // 64 M-tiles
    const int bnBase = (wg & 3) * 4;   // 4 consecutive N-tiles per block
    const int row0 = bm * 256;

    const int tid = threadIdx.x;
    const int lane = tid & 63, wave = tid >> 6;
    const int wr = wave >> 2, wc = wave & 3;      // 2M x 4N waves, 128x64 out each
    const int lrow = lane & 15, lhi = lane >> 4;  // MFMA fragment coords
    // 2-bit swizzled ds_read col (elems): row bits 2,3 -> flip 16,32 elems
    const int cX = (lhi * 8) ^ ((lrow & 4) << 2) ^ ((lrow & 8) << 2);
    const int rowA = wr * 128 + lrow;
    const int rowB = wc * 64 + lrow;
    const int wbase = wave * 512;                 // elems: wave*1024B staging slice

    // Per-lane staging source: linear LDS slot -> inverse-swizzled global col.
    // LDS row r = tid>>3 (+64/128 per inst/half): r&4 = tid&32, r&8 = tid&64.
    const int srow = tid >> 3;
    const int scol = ((tid & 7) * 8) ^ ((tid & 32) >> 1) ^ ((tid & 64) >> 1);
    const ushort* gAl = A + (size_t)(row0 + srow) * TK + scol;
    const ushort* gBl = B + (size_t)(bnBase * 256 + srow) * TK + scol;

    ushort* pA0 = lds;           // buf0 A (even K-tiles)
    ushort* pB0 = lds + 16384;   // buf0 B
    ushort* pA1 = lds + 32768;   // buf1 A (odd K-tiles)
    ushort* pB1 = lds + 49152;   // buf1 B

    bf16x8 af[4][2];  // current A quadrant (4 m-frags x 2 k-steps)
    bf16x8 bf[4][2];  // all B frags for current tile (4 n-frags x 2 k-steps)

    // Prologue: tile 0 A+B fully + tile 1 B; leave B(1) (last 4 insts) in flight.
    STAGE(pB0, BSRC(0), 0); STAGE(pB0, BSRC(0), 1);
    STAGE(pA0, ASRC(0), 0); STAGE(pA0, ASRC(0), 1);
    STAGE(pB1, BSRC(1), 0); STAGE(pB1, BSRC(1), 1);
    asm volatile("s_waitcnt vmcnt(4)" ::: "memory");
    __builtin_amdgcn_s_barrier();

#pragma unroll 1
    for (int j = 0; j < JT; ++j) {
        f32x4 acc[8][4];
#pragma unroll
        for (int m = 0; m < 8; ++m)
#pragma unroll
            for (int n = 0; n < 4; ++n)
                acc[m][n] = (f32x4){0.f, 0.f, 0.f, 0.f};

#pragma unroll 1
        for (int t = 0; t < NT; t += 2) {
            const int s = j * NT + t;  // staging stream position

            // ---- tile t (buf0) ----
            READA(pA0, 0); READB(pB0, 0);
            STAGE(pA1, ASRC(s + 1), 0);
            PH_SYNC; MFMA16(0, 0); PH_END;

            READB(pB0, 1);
            STAGE(pA1, ASRC(s + 1), 1);
            PH_SYNC; MFMA16(0, 1); PH_END;

            READA(pA0, 1);
            STAGE(pB0, BSRC(s + 2), 0);
            PH_SYNC; MFMA16(1, 0); PH_END;

            STAGE(pB0, BSRC(s + 2), 1);
            PH_SYNC; MFMA16(1, 1); PH_END_VM;   // leaves B(s+2) in flight

            // ---- tile t+1 (buf1) ----
            READA(pA1, 0); READB(pB1, 0);
            STAGE(pA0, ASRC(s + 2), 0);
            PH_SYNC; MFMA16(0, 0); PH_END;

            READB(pB1, 1);
            STAGE(pA0, ASRC(s + 2), 1);
            PH_SYNC; MFMA16(0, 1); PH_END;

            READA(pA1, 1);
            STAGE(pB1, BSRC(s + 3), 0);
            PH_SYNC; MFMA16(1, 0); PH_END;

            STAGE(pB1, BSRC(s + 3), 1);
            PH_SYNC; MFMA16(1, 1); PH_END_VM;   // leaves B(s+3) in flight
        }

        // Epilogue for tile j: next tile's first panels are already in flight
        // (staged by the K-loop tail). Stores are issued after those loads, so
        // the next iteration's vmcnt(4) guards remain valid (FIFO retirement).
        const int orow0 = row0 + wr * 128;
        const int ocol0 = (bnBase + j) * 256 + wc * 64;
        float csv[4], fsv[4];
        int cidx[4];
#pragma unroll
        for (int n = 0; n < 4; ++n) {
            const int c = ocol0 + n * 16 + lrow;
            cidx[n] = c;
            csv[n] = csq[c];
            fsv[n] = fsc[c];
        }
#pragma unroll
        for (int m = 0; m < 8; ++m) {
            const int rb = orow0 + m * 16 + lhi * 4;
            const f32x4 xs = *(const f32x4*)(xsq + rb);
            const float xv[4] = {xs.x, xs.y, xs.z, xs.w};
#pragma unroll
            for (int n = 0; n < 4; ++n) {
#pragma unroll
                for (int jj = 0; jj < 4; ++jj) {
                    float d2 = fmaxf(xv[jj] + csv[n] - 2.0f * acc[m][n][jj], 0.0f);
                    const float v = __expf(fsv[n] * d2);
                    __builtin_nontemporal_store(
                        v, out + (size_t)(rb + jj) * TN + cidx[n]);
                }
            }
        }
    }
}

extern "C" void kernel_launch(void* const* d_in, const int* in_sizes, int n_in,
                              void* d_out, int out_size, void* d_ws, size_t ws_size,
                              hipStream_t stream) {
    const float* inp = (const float*)d_in[0];  // [TM, TK]
    const float* ctr = (const float*)d_in[1];  // [TN, TK]
    const float* ls  = (const float*)d_in[2];  // [TN]
    float* out = (float*)d_out;

    // workspace layout (~42 MB)
    ushort* Abf = (ushort*)d_ws;
    ushort* Bbf = Abf + (size_t)TM * TK;
    float* xsq = (float*)(Bbf + (size_t)TN * TK);
    float* csq = xsq + TM;
    float* fsc = csq + TN;

    rowsq_cvt<<<TM, 256, 0, stream>>>(inp, Abf, xsq);
    rowsq_cvt<<<TN, 256, 0, stream>>>(ctr, Bbf, csq);
    scale_k<<<(TN + 255) / 256, 256, 0, stream>>>(ls, fsc);

    rbf_gemm<<<256, 512, 0, stream>>>(Abf, Bbf, xsq, csq, fsc, out);
}

// Round 6
// 208.867 us; speedup vs baseline: 1.0438x; 1.0438x over previous
//
#include <hip/hip_runtime.h>
#include <hip/hip_bf16.h>
#include <stdint.h>

// Problem constants (fixed by setup_inputs)
#define TM 16384   // B rows of input
#define TN 4096    // O centers
#define TK 1024    // I feature dim

#define NT (TK / 64)   // 16 K-tiles per output tile
#define JT 4           // output tiles per block (persistent along N)

typedef __attribute__((ext_vector_type(8))) short bf16x8;
typedef __attribute__((ext_vector_type(4))) float f32x4;

static __device__ __forceinline__ ushort f2bf(float x) {
    __hip_bfloat16 h = __float2bfloat16(x);
    return *reinterpret_cast<ushort*>(&h);
}

// Convert one fp32 row (TK elems) to bf16 and emit its sum of squares.
__global__ __launch_bounds__(256) void rowsq_cvt(const float* __restrict__ src,
                                                 ushort* __restrict__ dst,
                                                 float* __restrict__ sq) {
    const int row = blockIdx.x;
    const int t = threadIdx.x;
    const size_t base = (size_t)row * TK + (size_t)t * 4;
    const f32x4 v = __builtin_nontemporal_load((const f32x4*)(src + base));
    float s = v.x * v.x + v.y * v.y + v.z * v.z + v.w * v.w;

    ushort4 b;
    b.x = f2bf(v.x); b.y = f2bf(v.y); b.z = f2bf(v.z); b.w = f2bf(v.w);
    *(ushort4*)(dst + base) = b;

#pragma unroll
    for (int off = 32; off > 0; off >>= 1) s += __shfl_down(s, off);

    __shared__ float red[4];
    const int lane = t & 63, wave = t >> 6;
    if (lane == 0) red[wave] = s;
    __syncthreads();
    if (t == 0) sq[row] = red[0] + red[1] + red[2] + red[3];
}

// f[o] = -1/(2*sigma^2), sigma = exp(log_sigma)
__global__ __launch_bounds__(256) void scale_k(const float* __restrict__ ls,
                                               float* __restrict__ f) {
    const int i = blockIdx.x * 256 + threadIdx.x;
    if (i < TN) f[i] = -0.5f * expf(-2.0f * ls[i]);
}

// ---- persistent 8-phase 256x256 bf16 MFMA GEMM with fused RBF epilogue ----
// LDS: [buf][A|B] panels of 256x64 bf16 = 128 KiB. 2-bit XOR swizzle:
// physical byte p holds logical byte p ^ ((((p>>9)&1)<<5) | (((p>>10)&1)<<6))
// (row bits 2,3 -> byte bits 5,6; involution; applied on the global SOURCE at
// stage time and on the ds_read address). The k-step column offset is folded
// with XOR (cX ^ 32-elems), NOT addition — bit-6 carry corrupts the row
// otherwise (round-4 bug). Plain stores in the epilogue: nontemporal stores
// caused 1.45x write amplification AND stalled the vmcnt-guarded K-loop on
// slow HBM store retirement (round-5 regression).

#define STAGE(PAN, SRC, H) do {                                                \
    __builtin_amdgcn_global_load_lds(                                          \
        (const __attribute__((address_space(1))) void*)((SRC) + (size_t)(H) * 128 * TK), \
        (__attribute__((address_space(3))) void*)((PAN) + (H) * 8192 + wbase), \
        16, 0, 0);                                                             \
    __builtin_amdgcn_global_load_lds(                                          \
        (const __attribute__((address_space(1))) void*)((SRC) + (size_t)(H) * 128 * TK + 64 * TK), \
        (__attribute__((address_space(3))) void*)((PAN) + (H) * 8192 + 4096 + wbase), \
        16, 0, 0);                                                             \
} while (0)

// Staging-stream sources. A panel is identical for every output tile of this
// block (stream wraps &15). B panel advances along N every 16 K-tiles; wrap
// &63 keeps tail prefetch in-bounds (wrapped data is staged but never read).
#define ASRC(S) (gAl + (size_t)((S) & 15) * 64)
#define BSRC(S) (gBl + (size_t)(((S) & 63) >> 4) * (256 * (size_t)TK) + (size_t)((S) & 15) * 64)

#define READA(PAN, QM) do {                                                    \
    _Pragma("unroll") for (int _i = 0; _i < 4; ++_i)                           \
    _Pragma("unroll") for (int _k = 0; _k < 2; ++_k)                           \
        af[_i][_k] = *(const bf16x8*)((PAN) +                                  \
            (size_t)(rowA + (QM) * 64 + _i * 16) * 64 + (cX ^ (_k * 32)));     \
} while (0)

#define READB(PAN, QN) do {                                                    \
    _Pragma("unroll") for (int _n = 0; _n < 2; ++_n)                           \
    _Pragma("unroll") for (int _k = 0; _k < 2; ++_k)                           \
        bf[(QN) * 2 + _n][_k] = *(const bf16x8*)((PAN) +                       \
            (size_t)(rowB + (QN) * 32 + _n * 16) * 64 + (cX ^ (_k * 32)));     \
} while (0)

#define MFMA16(QM, QN)                                                         \
    _Pragma("unroll") for (int _i = 0; _i < 4; ++_i)                           \
    _Pragma("unroll") for (int _n = 0; _n < 2; ++_n)                           \
    _Pragma("unroll") for (int _k = 0; _k < 2; ++_k)                           \
        acc[(QM) * 4 + _i][(QN) * 2 + _n] =                                    \
            __builtin_amdgcn_mfma_f32_16x16x32_bf16(                           \
                af[_i][_k], bf[(QN) * 2 + _n][_k],                             \
                acc[(QM) * 4 + _i][(QN) * 2 + _n], 0, 0, 0)

#define PH_SYNC do {                                                           \
    __builtin_amdgcn_s_barrier();                                              \
    asm volatile("s_waitcnt lgkmcnt(0)" ::: "memory");                         \
    __builtin_amdgcn_sched_barrier(0);                                         \
    __builtin_amdgcn_s_setprio(1);                                             \
} while (0)

#define PH_END do {                                                            \
    __builtin_amdgcn_s_setprio(0);                                             \
    __builtin_amdgcn_s_barrier();                                              \
} while (0)

#define PH_END_VM do {                                                         \
    __builtin_amdgcn_s_setprio(0);                                             \
    asm volatile("s_waitcnt vmcnt(4)" ::: "memory");                           \
    __builtin_amdgcn_s_barrier();                                              \
} while (0)

__global__ __launch_bounds__(512) void rbf_gemm(const ushort* __restrict__ A,
                                                const ushort* __restrict__ B,
                                                const float* __restrict__ xsq,
                                                const float* __restrict__ csq,
                                                const float* __restrict__ fsc,
                                                float* __restrict__ out) {
    __shared__ __align__(16) ushort lds[65536];  // 128 KiB

    // 256 persistent blocks (1/CU), 8 XCDs x 32 contiguous wgs.
    // Same-bm blocks land on the same XCD (shared 512 KB A panel in L2).
    const int bid = blockIdx.x;
    const int wg = (bid & 7) * 32 + (bid >> 3);
    const int bm = wg >> 2;            // 64 M-tiles
    const int bnBase = (wg & 3) * 4;   // 4 consecutive N-tiles per block
    const int row0 = bm * 256;

    const int tid = threadIdx.x;
    const int lane = tid & 63, wave = tid >> 6;
    const int wr = wave >> 2, wc = wave & 3;      // 2M x 4N waves, 128x64 out each
    const int lrow = lane & 15, lhi = lane >> 4;  // MFMA fragment coords
    // 2-bit swizzled ds_read col (elems): row bits 2,3 -> flip 16,32 elems
    const int cX = (lhi * 8) ^ ((lrow & 4) << 2) ^ ((lrow & 8) << 2);
    const int rowA = wr * 128 + lrow;
    const int rowB = wc * 64 + lrow;
    const int wbase = wave * 512;                 // elems: wave*1024B staging slice

    // Per-lane staging source: linear LDS slot -> inverse-swizzled global col.
    // LDS row r = tid>>3 (+64/128 per inst/half): r&4 = tid&32, r&8 = tid&64.
    const int srow = tid >> 3;
    const int scol = ((tid & 7) * 8) ^ ((tid & 32) >> 1) ^ ((tid & 64) >> 1);
    const ushort* gAl = A + (size_t)(row0 + srow) * TK + scol;
    const ushort* gBl = B + (size_t)(bnBase * 256 + srow) * TK + scol;

    ushort* pA0 = lds;           // buf0 A (even K-tiles)
    ushort* pB0 = lds + 16384;   // buf0 B
    ushort* pA1 = lds + 32768;   // buf1 A (odd K-tiles)
    ushort* pB1 = lds + 49152;   // buf1 B

    bf16x8 af[4][2];  // current A quadrant (4 m-frags x 2 k-steps)
    bf16x8 bf[4][2];  // all B frags for current tile (4 n-frags x 2 k-steps)

    // Prologue: tile 0 A+B fully + tile 1 B; leave B(1) (last 4 insts) in flight.
    STAGE(pB0, BSRC(0), 0); STAGE(pB0, BSRC(0), 1);
    STAGE(pA0, ASRC(0), 0); STAGE(pA0, ASRC(0), 1);
    STAGE(pB1, BSRC(1), 0); STAGE(pB1, BSRC(1), 1);
    asm volatile("s_waitcnt vmcnt(4)" ::: "memory");
    __builtin_amdgcn_s_barrier();

#pragma unroll 1
    for (int j = 0; j < JT; ++j) {
        f32x4 acc[8][4];
#pragma unroll
        for (int m = 0; m < 8; ++m)
#pragma unroll
            for (int n = 0; n < 4; ++n)
                acc[m][n] = (f32x4){0.f, 0.f, 0.f, 0.f};

#pragma unroll 1
        for (int t = 0; t < NT; t += 2) {
            const int s = j * NT + t;  // staging stream position

            // ---- tile t (buf0) ----
            READA(pA0, 0); READB(pB0, 0);
            STAGE(pA1, ASRC(s + 1), 0);
            PH_SYNC; MFMA16(0, 0); PH_END;

            READB(pB0, 1);
            STAGE(pA1, ASRC(s + 1), 1);
            PH_SYNC; MFMA16(0, 1); PH_END;

            READA(pA0, 1);
            STAGE(pB0, BSRC(s + 2), 0);
            PH_SYNC; MFMA16(1, 0); PH_END;

            STAGE(pB0, BSRC(s + 2), 1);
            PH_SYNC; MFMA16(1, 1); PH_END_VM;   // leaves B(s+2) in flight

            // ---- tile t+1 (buf1) ----
            READA(pA1, 0); READB(pB1, 0);
            STAGE(pA0, ASRC(s + 2), 0);
            PH_SYNC; MFMA16(0, 0); PH_END;

            READB(pB1, 1);
            STAGE(pA0, ASRC(s + 2), 1);
            PH_SYNC; MFMA16(0, 1); PH_END;

            READA(pA1, 1);
            STAGE(pB1, BSRC(s + 3), 0);
            PH_SYNC; MFMA16(1, 0); PH_END;

            STAGE(pB1, BSRC(s + 3), 1);
            PH_SYNC; MFMA16(1, 1); PH_END_VM;   // leaves B(s+3) in flight
        }

        // Epilogue for tile j: next tile's first panels are already in flight
        // (staged by the K-loop tail). Stores are issued after those loads, so
        // the next iteration's vmcnt(4) guards remain valid (FIFO retirement);
        // plain stores retire to L2 quickly and overlap the next K-loop.
        const int orow0 = row0 + wr * 128;
        const int ocol0 = (bnBase + j) * 256 + wc * 64;
        float csv[4], fsv[4];
        int cidx[4];
#pragma unroll
        for (int n = 0; n < 4; ++n) {
            const int c = ocol0 + n * 16 + lrow;
            cidx[n] = c;
            csv[n] = csq[c];
            fsv[n] = fsc[c];
        }
#pragma unroll
        for (int m = 0; m < 8; ++m) {
            const int rb = orow0 + m * 16 + lhi * 4;
            const f32x4 xs = *(const f32x4*)(xsq + rb);
            const float xv[4] = {xs.x, xs.y, xs.z, xs.w};
#pragma unroll
            for (int n = 0; n < 4; ++n) {
#pragma unroll
                for (int jj = 0; jj < 4; ++jj) {
                    float d2 = fmaxf(xv[jj] + csv[n] - 2.0f * acc[m][n][jj], 0.0f);
                    out[(size_t)(rb + jj) * TN + cidx[n]] = __expf(fsv[n] * d2);
                }
            }
        }
    }
}

extern "C" void kernel_launch(void* const* d_in, const int* in_sizes, int n_in,
                              void* d_out, int out_size, void* d_ws, size_t ws_size,
                              hipStream_t stream) {
    const float* inp = (const float*)d_in[0];  // [TM, TK]
    const float* ctr = (const float*)d_in[1];  // [TN, TK]
    const float* ls  = (const float*)d_in[2];  // [TN]
    float* out = (float*)d_out;

    // workspace layout (~42 MB)
    ushort* Abf = (ushort*)d_ws;
    ushort* Bbf = Abf + (size_t)TM * TK;
    float* xsq = (float*)(Bbf + (size_t)TN * TK);
    float* csq = xsq + TM;
    float* fsc = csq + TN;

    rowsq_cvt<<<TM, 256, 0, stream>>>(inp, Abf, xsq);
    rowsq_cvt<<<TN, 256, 0, stream>>>(ctr, Bbf, csq);
    scale_k<<<(TN + 255) / 256, 256, 0, stream>>>(ls, fsc);

    rbf_gemm<<<256, 512, 0, stream>>>(Abf, Bbf, xsq, csq, fsc, out);
}

// Round 7
// 190.448 us; speedup vs baseline: 1.1447x; 1.0967x over previous
//
#include <hip/hip_runtime.h>
#include <hip/hip_bf16.h>
#include <stdint.h>

// Problem constants (fixed by setup_inputs)
#define TM 16384   // B rows of input
#define TN 4096    // O centers
#define TK 1024    // I feature dim

#define NT (TK / 64)   // 16 K-tiles per output tile
#define JT 4           // center tiles per block (persistent along O)

typedef __attribute__((ext_vector_type(8))) short bf16x8;
typedef __attribute__((ext_vector_type(4))) float f32x4;

static __device__ __forceinline__ ushort f2bf(float x) {
    __hip_bfloat16 h = __float2bfloat16(x);
    return *reinterpret_cast<ushort*>(&h);
}

// Convert one fp32 row (TK elems) to bf16 and emit its sum of squares.
__global__ __launch_bounds__(256) void rowsq_cvt(const float* __restrict__ src,
                                                 ushort* __restrict__ dst,
                                                 float* __restrict__ sq) {
    const int row = blockIdx.x;
    const int t = threadIdx.x;
    const size_t base = (size_t)row * TK + (size_t)t * 4;
    const f32x4 v = __builtin_nontemporal_load((const f32x4*)(src + base));
    float s = v.x * v.x + v.y * v.y + v.z * v.z + v.w * v.w;

    ushort4 b;
    b.x = f2bf(v.x); b.y = f2bf(v.y); b.z = f2bf(v.z); b.w = f2bf(v.w);
    *(ushort4*)(dst + base) = b;

#pragma unroll
    for (int off = 32; off > 0; off >>= 1) s += __shfl_down(s, off);

    __shared__ float red[4];
    const int lane = t & 63, wave = t >> 6;
    if (lane == 0) red[wave] = s;
    __syncthreads();
    if (t == 0) sq[row] = red[0] + red[1] + red[2] + red[3];
}

// f[o] = -1/(2*sigma^2), sigma = exp(log_sigma)
__global__ __launch_bounds__(256) void scale_k(const float* __restrict__ ls,
                                               float* __restrict__ f) {
    const int i = blockIdx.x * 256 + threadIdx.x;
    if (i < TN) f[i] = -0.5f * expf(-2.0f * ls[i]);
}

// ---- persistent 8-phase 256x256 bf16 MFMA GEMM with fused RBF epilogue ----
// OPERAND-SWAPPED: A-operand = centers panel, B-operand = input panel, so the
// MFMA C-layout's contiguous dim (row = lhi*4+reg) is the centers/output-col
// dim -> epilogue stores are contiguous f32x4 (32 insts/thread vs 128 scalar;
// round-6 lesson: scalar stores inside the vmcnt window amplified writes and
// stalled ph4's vmcnt(4), since gfx9 vmcnt counts stores).
// LDS: [buf][A|B] panels of 256x64 bf16 = 128 KiB. 2-bit XOR swizzle:
// physical byte p holds logical byte p ^ ((((p>>9)&1)<<5) | (((p>>10)&1)<<6));
// k-step column offset folded with XOR (cX ^ 32-elems), NOT addition (bit-6
// carry corrupts the row - round-4 bug).

#define STAGE(PAN, SRC, H) do {                                                \
    __builtin_amdgcn_global_load_lds(                                          \
        (const __attribute__((address_space(1))) void*)((SRC) + (size_t)(H) * 128 * TK), \
        (__attribute__((address_space(3))) void*)((PAN) + (H) * 8192 + wbase), \
        16, 0, 0);                                                             \
    __builtin_amdgcn_global_load_lds(                                          \
        (const __attribute__((address_space(1))) void*)((SRC) + (size_t)(H) * 128 * TK + 64 * TK), \
        (__attribute__((address_space(3))) void*)((PAN) + (H) * 8192 + 4096 + wbase), \
        16, 0, 0);                                                             \
} while (0)

// Staging-stream sources. A-stream = CENTERS: advances to the next 256-row
// center tile every 16 K-tiles (persistent dim). B-stream = INPUT panel,
// identical every j (wraps &15). Wrap &63 keeps the j=3 tail prefetch
// in-bounds (wrapped data is staged but never read).
#define ASRC(S) (gAl + (size_t)(((S) & 63) >> 4) * (256 * (size_t)TK) + (size_t)((S) & 15) * 64)
#define BSRC(S) (gBl + (size_t)((S) & 15) * 64)

#define READA(PAN, QM) do {                                                    \
    _Pragma("unroll") for (int _i = 0; _i < 4; ++_i)                           \
    _Pragma("unroll") for (int _k = 0; _k < 2; ++_k)                           \
        af[_i][_k] = *(const bf16x8*)((PAN) +                                  \
            (size_t)(rowA + (QM) * 64 + _i * 16) * 64 + (cX ^ (_k * 32)));     \
} while (0)

#define READB(PAN, QN) do {                                                    \
    _Pragma("unroll") for (int _n = 0; _n < 2; ++_n)                           \
    _Pragma("unroll") for (int _k = 0; _k < 2; ++_k)                           \
        bf[(QN) * 2 + _n][_k] = *(const bf16x8*)((PAN) +                       \
            (size_t)(rowB + (QN) * 32 + _n * 16) * 64 + (cX ^ (_k * 32)));     \
} while (0)

#define MFMA16(QM, QN)                                                         \
    _Pragma("unroll") for (int _i = 0; _i < 4; ++_i)                           \
    _Pragma("unroll") for (int _n = 0; _n < 2; ++_n)                           \
    _Pragma("unroll") for (int _k = 0; _k < 2; ++_k)                           \
        acc[(QM) * 4 + _i][(QN) * 2 + _n] =                                    \
            __builtin_amdgcn_mfma_f32_16x16x32_bf16(                           \
                af[_i][_k], bf[(QN) * 2 + _n][_k],                             \
                acc[(QM) * 4 + _i][(QN) * 2 + _n], 0, 0, 0)

#define PH_SYNC do {                                                           \
    __builtin_amdgcn_s_barrier();                                              \
    asm volatile("s_waitcnt lgkmcnt(0)" ::: "memory");                         \
    __builtin_amdgcn_sched_barrier(0);                                         \
    __builtin_amdgcn_s_setprio(1);                                             \
} while (0)

#define PH_END do {                                                            \
    __builtin_amdgcn_s_setprio(0);                                             \
    __builtin_amdgcn_s_barrier();                                              \
} while (0)

#define PH_END_VM do {                                                         \
    __builtin_amdgcn_s_setprio(0);                                             \
    asm volatile("s_waitcnt vmcnt(4)" ::: "memory");                           \
    __builtin_amdgcn_s_barrier();                                              \
} while (0)

__global__ __launch_bounds__(512) void rbf_gemm(const ushort* __restrict__ Cb,  // centers bf16 [TN][TK]
                                                const ushort* __restrict__ Xb,  // input   bf16 [TM][TK]
                                                const float* __restrict__ xsq,
                                                const float* __restrict__ csq,
                                                const float* __restrict__ fsc,
                                                float* __restrict__ out) {
    __shared__ __align__(16) ushort lds[65536];  // 128 KiB

    // 256 persistent blocks (1/CU). Per XCD (32 consecutive wg): 8 input
    // panels x 4 jbase groups; the 8 blocks sharing a jbase group stream the
    // SAME 4 center tiles in lockstep -> 1 L2 miss + 7 hits.
    const int bid = blockIdx.x;
    const int wg = (bid & 7) * 32 + (bid >> 3);
    const int bm = wg >> 2;            // 64 input tiles (rows of out)
    const int jbase = (wg & 3) * 4;    // first of 4 center tiles (cols of out)
    const int rowx0 = bm * 256;

    const int tid = threadIdx.x;
    const int lane = tid & 63, wave = tid >> 6;
    const int wr = wave >> 2, wc = wave & 3;      // wr: center-dim, wc: input-dim
    const int lrow = lane & 15, lhi = lane >> 4;  // MFMA fragment coords
    // 2-bit swizzled ds_read col (elems): row bits 2,3 -> flip 16,32 elems
    const int cX = (lhi * 8) ^ ((lrow & 4) << 2) ^ ((lrow & 8) << 2);
    const int rowA = wr * 128 + lrow;             // centers panel row
    const int rowB = wc * 64 + lrow;              // input panel row
    const int wbase = wave * 512;                 // elems: wave*1024B staging slice

    // Per-lane staging source: linear LDS slot -> inverse-swizzled global col.
    const int srow = tid >> 3;
    const int scol = ((tid & 7) * 8) ^ ((tid & 32) >> 1) ^ ((tid & 64) >> 1);
    const ushort* gAl = Cb + (size_t)(jbase * 256 + srow) * TK + scol;  // centers stream
    const ushort* gBl = Xb + (size_t)(rowx0 + srow) * TK + scol;        // input panel

    ushort* pA0 = lds;           // buf0 A (even K-tiles)
    ushort* pB0 = lds + 16384;   // buf0 B
    ushort* pA1 = lds + 32768;   // buf1 A (odd K-tiles)
    ushort* pB1 = lds + 49152;   // buf1 B

    bf16x8 af[4][2];  // current A (centers) quadrant
    bf16x8 bf[4][2];  // all B (input) frags for current tile

    // Prologue: tile 0 A+B fully + tile 1 B; leave B(1) (last 4 insts) in flight.
    STAGE(pB0, BSRC(0), 0); STAGE(pB0, BSRC(0), 1);
    STAGE(pA0, ASRC(0), 0); STAGE(pA0, ASRC(0), 1);
    STAGE(pB1, BSRC(1), 0); STAGE(pB1, BSRC(1), 1);
    asm volatile("s_waitcnt vmcnt(4)" ::: "memory");
    __builtin_amdgcn_s_barrier();

#pragma unroll 1
    for (int j = 0; j < JT; ++j) {
        f32x4 acc[8][4];
#pragma unroll
        for (int m = 0; m < 8; ++m)
#pragma unroll
            for (int n = 0; n < 4; ++n)
                acc[m][n] = (f32x4){0.f, 0.f, 0.f, 0.f};

#pragma unroll 1
        for (int t = 0; t < NT; t += 2) {
            const int s = j * NT + t;  // staging stream position

            // ---- tile t (buf0) ----
            READA(pA0, 0); READB(pB0, 0);
            STAGE(pA1, ASRC(s + 1), 0);
            PH_SYNC; MFMA16(0, 0); PH_END;

            READB(pB0, 1);
            STAGE(pA1, ASRC(s + 1), 1);
            PH_SYNC; MFMA16(0, 1); PH_END;

            READA(pA0, 1);
            STAGE(pB0, BSRC(s + 2), 0);
            PH_SYNC; MFMA16(1, 0); PH_END;

            STAGE(pB0, BSRC(s + 2), 1);
            PH_SYNC; MFMA16(1, 1); PH_END_VM;   // leaves B(s+2) in flight

            // ---- tile t+1 (buf1) ----
            READA(pA1, 0); READB(pB1, 0);
            STAGE(pA0, ASRC(s + 2), 0);
            PH_SYNC; MFMA16(0, 0); PH_END;

            READB(pB1, 1);
            STAGE(pA0, ASRC(s + 2), 1);
            PH_SYNC; MFMA16(0, 1); PH_END;

            READA(pA1, 1);
            STAGE(pB1, BSRC(s + 3), 0);
            PH_SYNC; MFMA16(1, 0); PH_END;

            STAGE(pB1, BSRC(s + 3), 1);
            PH_SYNC; MFMA16(1, 1); PH_END_VM;   // leaves B(s+3) in flight
        }

        // Epilogue for center tile j: acc element (m,n,jj) is
        // cross[o = o0 + m*16 + lhi*4 + jj][b = b0 + n*16 + lrow].
        // Contiguous f32x4 store per (m,n). Next tile's panels already in
        // flight; stores (32/thread) drain cheaply before next ph4 vmcnt(4).
        const int o0 = (jbase + j) * 256 + wr * 128;
        const int b0 = rowx0 + wc * 64;
#pragma unroll
        for (int m = 0; m < 8; ++m) {
            const int o4 = o0 + m * 16 + lhi * 4;
            const f32x4 cs4 = *(const f32x4*)(csq + o4);
            const f32x4 fs4 = *(const f32x4*)(fsc + o4);
#pragma unroll
            for (int n = 0; n < 4; ++n) {
                const int b = b0 + n * 16 + lrow;
                const float xs = xsq[b];
                f32x4 v;
#pragma unroll
                for (int jj = 0; jj < 4; ++jj) {
                    float d2 = fmaxf(xs + cs4[jj] - 2.0f * acc[m][n][jj], 0.0f);
                    v[jj] = __expf(fs4[jj] * d2);
                }
                *(f32x4*)(out + (size_t)b * TN + o4) = v;
            }
        }
    }
}

extern "C" void kernel_launch(void* const* d_in, const int* in_sizes, int n_in,
                              void* d_out, int out_size, void* d_ws, size_t ws_size,
                              hipStream_t stream) {
    const float* inp = (const float*)d_in[0];  // [TM, TK]
    const float* ctr = (const float*)d_in[1];  // [TN, TK]
    const float* ls  = (const float*)d_in[2];  // [TN]
    float* out = (float*)d_out;

    // workspace layout (~42 MB)
    ushort* Abf = (ushort*)d_ws;
    ushort* Bbf = Abf + (size_t)TM * TK;
    float* xsq = (float*)(Bbf + (size_t)TN * TK);
    float* csq = xsq + TM;
    float* fsc = csq + TN;

    rowsq_cvt<<<TM, 256, 0, stream>>>(inp, Abf, xsq);
    rowsq_cvt<<<TN, 256, 0, stream>>>(ctr, Bbf, csq);
    scale_k<<<(TN + 255) / 256, 256, 0, stream>>>(ls, fsc);

    rbf_gemm<<<256, 512, 0, stream>>>(Bbf, Abf, xsq, csq, fsc, out);
}